// Round 5
// baseline (1378.680 us; speedup 1.0000x reference)
//
#include <hip/hip_runtime.h>
#include <hip/hip_bf16.h>

#define N_CTX 4096
#define DM    2048

typedef __attribute__((ext_vector_type(8))) short short8;
typedef __attribute__((ext_vector_type(4))) float f32x4;
typedef unsigned short ushort_t;

#define WBAR() __builtin_amdgcn_s_barrier()

__device__ __forceinline__ ushort_t f2bf(float x) {
    __hip_bfloat16 h = __float2bfloat16(x);
    return __builtin_bit_cast(ushort_t, h);
}
__device__ __forceinline__ float bf2f(ushort_t u) {
    return __bfloat162float(__builtin_bit_cast(__hip_bfloat16, u));
}

__device__ __forceinline__ void gload16(const void* g, void* l) {
    __builtin_amdgcn_global_load_lds((const __attribute__((address_space(1))) void*)g,
                                     (__attribute__((address_space(3))) void*)l,
                                     16, 0, 0);
}

// ---------------- cast kernels ----------------

__global__ __launch_bounds__(256) void split_cast_kernel(
    const float* __restrict__ in, ushort_t* __restrict__ hi, ushort_t* __restrict__ lo, int n4)
{
    int idx = blockIdx.x * 256 + threadIdx.x;
    if (idx >= n4) return;
    float4 v = reinterpret_cast<const float4*>(in)[idx];
    float vv[4] = {v.x, v.y, v.z, v.w};
    ushort_t h[4], l[4];
#pragma unroll
    for (int j = 0; j < 4; ++j) {
        h[j] = f2bf(vv[j]);
        l[j] = f2bf(vv[j] - bf2f(h[j]));
    }
    reinterpret_cast<ushort4*>(hi)[idx] = *reinterpret_cast<ushort4*>(h);
    reinterpret_cast<ushort4*>(lo)[idx] = *reinterpret_cast<ushort4*>(l);
}

template <bool SPLIT>
__global__ __launch_bounds__(256) void transpose_cast_kernel(
    const float* __restrict__ in, ushort_t* __restrict__ hi, ushort_t* __restrict__ lo,
    int R, int C)
{
    __shared__ float tile[32][33];
    int bc = blockIdx.x * 32;
    int br = blockIdx.y * 32;
    int tx = threadIdx.x, ty = threadIdx.y;   // (32, 8)
#pragma unroll
    for (int r = ty; r < 32; r += 8)
        tile[r][tx] = in[(size_t)(br + r) * C + bc + tx];
    __syncthreads();
#pragma unroll
    for (int c = ty; c < 32; c += 8) {
        float v = tile[tx][c];
        size_t o = (size_t)(bc + c) * R + br + tx;
        ushort_t h = f2bf(v);
        hi[o] = h;
        if (SPLIT) lo[o] = f2bf(v - bf2f(h));
    }
}

// ---------------- 8-phase 256x128 GEMM ----------------
// C[M][N] = sum_p A_p @ B_p^T ; A_p: [M][K] bf16 row-major, B_p: [N][K] bf16.
// BM=256, BN=128, BK=64. 8 waves (4M x 2N), per-wave 64x64 output.
// LDS: Abuf[2] 32KB each @0/32K, Bbuf[2] 16KB each @64K/80K = 96KB.
// m201-faithful phase template: {ds_read -> s_barrier -> lgkmcnt(0) ->
// sched_barrier(0) -> setprio(1) MFMA setprio(0) -> s_barrier}. Stage (6
// gload_lds) + counted vmcnt(6) only in P4/P8 — never drained to 0 in-loop,
// no other sched_barrier pinning (m141 lesson).
// OM: 0=f32 out, 1=bf16 out, 2=split bf16 out. CAUSAL: skip blocks above diag.
// CKLIM: limit K to (by+1)*256 (A columns beyond are zero — causal attn rows).

template <int NP, int OM, bool CAUSAL, bool CKLIM>
__global__ __launch_bounds__(512, 2) void gemm8_kernel(
    const ushort_t* __restrict__ A0, const ushort_t* __restrict__ B0,
    const ushort_t* __restrict__ A1, const ushort_t* __restrict__ B1,
    const ushort_t* __restrict__ A2, const ushort_t* __restrict__ B2,
    int K, int kshift, int nbxs, int ldc,
    float* __restrict__ Cf, ushort_t* __restrict__ Ch, ushort_t* __restrict__ Cl)
{
    extern __shared__ char lds[];

    // bijective XCD swizzle (grids are multiples of 8)
    const int nwg = gridDim.x;
    const int q8 = nwg >> 3;
    const int wgid = (blockIdx.x & 7) * q8 + (blockIdx.x >> 3);
    const int by = wgid >> nbxs;
    const int bx = wgid & ((1 << nbxs) - 1);
    if (CAUSAL && bx * 128 > by * 256 + 255) return;

    const int t = threadIdx.x;
    const int l = t & 63;
    const int w = t >> 6;
    const int wr = w >> 1;          // 0..3 -> 64-row band
    const int wc = w & 1;           // 0..1 -> 64-col band
    const int lr = l & 15;
    const int lc = l >> 4;

    const size_t arow0 = (size_t)by * 256;
    const size_t brow0 = (size_t)bx * 128;

    int ntiles = (NP * K) >> 6;
    if (CKLIM) { int lim = (by + 1) * 4; if (lim < ntiles) ntiles = lim; }
    const int kmask = (K >> 6) - 1;   // per-pair K-tiles - 1 (power of 2)

    f32x4 acc[4][4];
#pragma unroll
    for (int m = 0; m < 4; ++m)
#pragma unroll
        for (int n = 0; n < 4; ++n) acc[m][n] = (f32x4){0.f, 0.f, 0.f, 0.f};

    auto stage = [&](int T, int buf) {
        int p = (NP > 1) ? (T >> kshift) : 0;
        int kt = (T & kmask) << 6;
        const ushort_t* Ap = A0; const ushort_t* Bp = B0;
        if (NP > 1 && p == 1) { Ap = A1; Bp = B1; }
        if (NP > 2 && p == 2) { Ap = A2; Bp = B2; }
        char* ab = lds + buf * 32768;
#pragma unroll
        for (int i = 0; i < 4; ++i) {
            int f = i * 512 + t;
            int row = f >> 3, c = f & 7;
            gload16(Ap + (arow0 + row) * (size_t)K + kt + ((c ^ (row & 7)) << 3),
                    ab + f * 16);
        }
        char* bb = lds + 65536 + buf * 16384;
#pragma unroll
        for (int i = 0; i < 2; ++i) {
            int f = i * 512 + t;
            int row = f >> 3, c = f & 7;
            gload16(Bp + (brow0 + row) * (size_t)K + kt + ((c ^ (row & 7)) << 3),
                    bb + f * 16);
        }
    };

    auto rdA = [&](short8* d, int mb, int buf) {
        const char* base = lds + buf * 32768;
#pragma unroll
        for (int mi = 0; mi < 2; ++mi)
#pragma unroll
            for (int kk = 0; kk < 2; ++kk) {
                int row = wr * 64 + (mb + mi) * 16 + lr;
                d[mi * 2 + kk] = *(const short8*)(base + row * 128 +
                                  ((((kk << 2) + lc) ^ (lr & 7)) << 4));
            }
    };
    auto rdB = [&](short8* d, int nb, int buf) {
        const char* base = lds + 65536 + buf * 16384;
#pragma unroll
        for (int ni = 0; ni < 2; ++ni)
#pragma unroll
            for (int kk = 0; kk < 2; ++kk) {
                int row = wc * 64 + (nb + ni) * 16 + lr;
                d[ni * 2 + kk] = *(const short8*)(base + row * 128 +
                                  ((((kk << 2) + lc) ^ (lr & 7)) << 4));
            }
    };
    auto mm8 = [&](const short8* a, const short8* b, int mb, int nb) {
#pragma unroll
        for (int mi = 0; mi < 2; ++mi)
#pragma unroll
            for (int ni = 0; ni < 2; ++ni)
#pragma unroll
                for (int kk = 0; kk < 2; ++kk)
                    acc[mb + mi][nb + ni] = __builtin_amdgcn_mfma_f32_16x16x32_bf16(
                        a[mi * 2 + kk], b[ni * 2 + kk], acc[mb + mi][nb + ni], 0, 0, 0);
    };

    // prologue: stage tiles 0,1; wait tile 0 (tile 1's 6 loads stay in flight)
    stage(0, 0);
    stage(ntiles > 1 ? 1 : 0, 1);
    asm volatile("s_waitcnt vmcnt(6)" ::: "memory");
    WBAR();

    const int nit = ntiles >> 1;   // ntiles always even here
    for (int it = 0; it < nit; ++it) {
        int T2 = 2 * it + 2; if (T2 > ntiles - 1) T2 = ntiles - 1;
        int T3 = 2 * it + 3; if (T3 > ntiles - 1) T3 = ntiles - 1;
#pragma unroll
        for (int h = 0; h < 2; ++h) {
            const int buf = h;
            const int Tp = h ? T3 : T2;
            short8 a01[4], a23[4], b01[4], b23[4];
            // P1: rd A01+B01 ; mfma q(0,0)
            rdA(a01, 0, buf); rdB(b01, 0, buf);
            WBAR();
            asm volatile("s_waitcnt lgkmcnt(0)" ::: "memory");
            __builtin_amdgcn_sched_barrier(0);
            __builtin_amdgcn_s_setprio(1); mm8(a01, b01, 0, 0); __builtin_amdgcn_s_setprio(0);
            WBAR();
            // P2: rd B23 ; mfma q(0,1)
            rdB(b23, 2, buf);
            WBAR();
            asm volatile("s_waitcnt lgkmcnt(0)" ::: "memory");
            __builtin_amdgcn_sched_barrier(0);
            __builtin_amdgcn_s_setprio(1); mm8(a01, b23, 0, 2); __builtin_amdgcn_s_setprio(0);
            WBAR();
            // P3: rd A23 ; mfma q(1,1)
            rdA(a23, 2, buf);
            WBAR();
            asm volatile("s_waitcnt lgkmcnt(0)" ::: "memory");
            __builtin_amdgcn_sched_barrier(0);
            __builtin_amdgcn_s_setprio(1); mm8(a23, b23, 2, 2); __builtin_amdgcn_s_setprio(0);
            WBAR();
            // P4: prefetch tile Tp into this buf (its reads completed by P3's
            // closing barrier), counted vmcnt — tile T+1 guaranteed landed.
            stage(Tp, buf);
            asm volatile("s_waitcnt vmcnt(6)" ::: "memory");
            WBAR();
            __builtin_amdgcn_s_setprio(1); mm8(a23, b01, 2, 0); __builtin_amdgcn_s_setprio(0);
            WBAR();
        }
    }

    // epilogue: C/D layout col = lane&15, row = (lane>>4)*4 + reg
    const int r0 = by * 256 + wr * 64 + (lc << 2);
    const int c0 = bx * 128 + wc * 64 + lr;
#pragma unroll
    for (int m = 0; m < 4; ++m)
#pragma unroll
        for (int n = 0; n < 4; ++n)
#pragma unroll
            for (int j = 0; j < 4; ++j) {
                size_t o = (size_t)(r0 + m * 16 + j) * ldc + (c0 + n * 16);
                float v = acc[m][n][j];
                if (OM == 0) {
                    Cf[o] = v;
                } else if (OM == 1) {
                    Ch[o] = f2bf(v);
                } else {
                    ushort_t hh = f2bf(v);
                    Ch[o] = hh;
                    Cl[o] = f2bf(v - bf2f(hh));
                }
            }
}

// ---------------- causal row softmax ----------------

__device__ __forceinline__ float waveMax(float v) {
#pragma unroll
    for (int o = 32; o > 0; o >>= 1) v = fmaxf(v, __shfl_xor(v, o, 64));
    return v;
}
__device__ __forceinline__ float waveSum(float v) {
#pragma unroll
    for (int o = 32; o > 0; o >>= 1) v += __shfl_xor(v, o, 64);
    return v;
}

__global__ __launch_bounds__(256) void softmax_kernel(
    const float* __restrict__ S, ushort_t* __restrict__ A)
{
    const int i = blockIdx.x;
    __shared__ float row[N_CTX];
    __shared__ float red[8];
    const int t = threadIdx.x;
    const int len = i + 1;
    const float* Srow = S + (size_t)i * N_CTX;

    float m = -3.4e38f;
    for (int j = t; j < len; j += 256) {
        float v = Srow[j];
        row[j] = v;
        m = fmaxf(m, v);
    }
    m = waveMax(m);
    if ((t & 63) == 0) red[t >> 6] = m;
    __syncthreads();
    m = fmaxf(fmaxf(red[0], red[1]), fmaxf(red[2], red[3]));

    float s = 0.f;
    for (int j = t; j < len; j += 256) {
        float e = __expf(row[j] - m);
        row[j] = e;
        s += e;
    }
    s = waveSum(s);
    __syncthreads();
    if ((t & 63) == 0) red[t >> 6] = s;
    __syncthreads();
    float inv = 1.f / (red[0] + red[1] + red[2] + red[3]);

    ushort_t* Arow = A + (size_t)i * N_CTX;
    for (int j = t; j < N_CTX; j += 256)
        Arow[j] = (j < len) ? f2bf(row[j] * inv) : (ushort_t)0;
}

// ---------------- launcher ----------------

extern "C" void kernel_launch(void* const* d_in, const int* in_sizes, int n_in,
                              void* d_out, int out_size, void* d_ws, size_t ws_size,
                              hipStream_t stream)
{
    const float* E  = (const float*)d_in[0];
    const float* qk = (const float*)d_in[1];
    const float* ov = (const float*)d_in[2];
    float* out = (float*)d_out;

    char* ws = (char*)d_ws;
    size_t off = 0;
    auto take = [&](size_t bytes) -> char* {
        char* p = ws + off;
        off += (bytes + 255) & ~(size_t)255;
        return p;
    };

    ushort_t* Ehi   = (ushort_t*)take((size_t)N_CTX * DM * 2);
    ushort_t* Elo   = (ushort_t*)take((size_t)N_CTX * DM * 2);
    ushort_t* Et    = (ushort_t*)take((size_t)N_CTX * DM * 2);
    ushort_t* QKthi = (ushort_t*)take((size_t)DM * DM * 2);
    ushort_t* QKtlo = (ushort_t*)take((size_t)DM * DM * 2);
    ushort_t* OVt   = (ushort_t*)take((size_t)DM * DM * 2);
    ushort_t* Qhi   = (ushort_t*)take((size_t)N_CTX * DM * 2);
    ushort_t* Qlo   = (ushort_t*)take((size_t)N_CTX * DM * 2);
    float*    S     = (float*)take((size_t)N_CTX * N_CTX * 4);
    ushort_t* Attn  = (ushort_t*)take((size_t)N_CTX * N_CTX * 2);
    ushort_t* Hbf   = (ushort_t*)take((size_t)N_CTX * DM * 2);
    (void)ws_size; (void)in_sizes; (void)n_in; (void)out_size;

    constexpr int SMEM = 96 * 1024;
    hipFuncSetAttribute((const void*)&gemm8_kernel<3, 2, false, false>,
                        hipFuncAttributeMaxDynamicSharedMemorySize, SMEM);
    hipFuncSetAttribute((const void*)&gemm8_kernel<3, 0, true, false>,
                        hipFuncAttributeMaxDynamicSharedMemorySize, SMEM);
    hipFuncSetAttribute((const void*)&gemm8_kernel<1, 1, false, true>,
                        hipFuncAttributeMaxDynamicSharedMemorySize, SMEM);
    hipFuncSetAttribute((const void*)&gemm8_kernel<1, 0, false, false>,
                        hipFuncAttributeMaxDynamicSharedMemorySize, SMEM);

    // 1. casts
    split_cast_kernel<<<dim3((N_CTX * DM / 4) / 256), 256, 0, stream>>>(E, Ehi, Elo, N_CTX * DM / 4);
    transpose_cast_kernel<true ><<<dim3(DM / 32, DM / 32),    dim3(32, 8), 0, stream>>>(qk, QKthi, QKtlo, DM, DM);
    transpose_cast_kernel<false><<<dim3(DM / 32, DM / 32),    dim3(32, 8), 0, stream>>>(ov, OVt, nullptr, DM, DM);
    transpose_cast_kernel<false><<<dim3(DM / 32, N_CTX / 32), dim3(32, 8), 0, stream>>>(E, Et, nullptr, N_CTX, DM);

    // 2. Q = E @ qk (3-pair split, split bf16 out). grid 16x16=256
    gemm8_kernel<3, 2, false, false><<<256, 512, SMEM, stream>>>(
        Ehi, QKthi, Ehi, QKtlo, Elo, QKthi, DM, 5, 4, DM, nullptr, Qhi, Qlo);

    // 3. S = Q @ E^T (3-pair split, causal, f32 out). grid 16x32=512
    gemm8_kernel<3, 0, true, false><<<512, 512, SMEM, stream>>>(
        Qhi, Ehi, Qhi, Elo, Qlo, Ehi, DM, 5, 5, N_CTX, S, nullptr, nullptr);

    // 4. attn = causal softmax(S)
    softmax_kernel<<<N_CTX, 256, 0, stream>>>(S, Attn);

    // 5. H = attn @ E (bf16 out, causal K-limit). grid 16x16=256
    gemm8_kernel<1, 1, false, true><<<256, 512, SMEM, stream>>>(
        Attn, Et, nullptr, nullptr, nullptr, nullptr, N_CTX, 6, 4, DM, nullptr, Hbf, nullptr);

    // 6. out = H @ ov (f32 out). grid 16x16=256
    gemm8_kernel<1, 0, false, false><<<256, 512, SMEM, stream>>>(
        Hbf, OVt, nullptr, nullptr, nullptr, nullptr, DM, 5, 4, DM, out, nullptr, nullptr);
}

// Round 6
// 469.026 us; speedup vs baseline: 2.9395x; 2.9395x over previous
//
#include <hip/hip_runtime.h>
#include <hip/hip_bf16.h>

#define N_CTX 4096
#define DM    2048

typedef __attribute__((ext_vector_type(8))) short short8;
typedef __attribute__((ext_vector_type(4))) float f32x4;
typedef unsigned short ushort_t;

__device__ __forceinline__ ushort_t f2bf(float x) {
    __hip_bfloat16 h = __float2bfloat16(x);
    return __builtin_bit_cast(ushort_t, h);
}
__device__ __forceinline__ float bf2f(ushort_t u) {
    return __bfloat162float(__builtin_bit_cast(__hip_bfloat16, u));
}

__device__ __forceinline__ void gload16(const void* g, void* l) {
    __builtin_amdgcn_global_load_lds((const __attribute__((address_space(1))) void*)g,
                                     (__attribute__((address_space(3))) void*)l,
                                     16, 0, 0);
}

// ---------------- cast kernels ----------------

__global__ __launch_bounds__(256) void split_cast_kernel(
    const float* __restrict__ in, ushort_t* __restrict__ hi, ushort_t* __restrict__ lo, int n4)
{
    int idx = blockIdx.x * 256 + threadIdx.x;
    if (idx >= n4) return;
    float4 v = reinterpret_cast<const float4*>(in)[idx];
    float vv[4] = {v.x, v.y, v.z, v.w};
    ushort_t h[4], l[4];
#pragma unroll
    for (int j = 0; j < 4; ++j) {
        h[j] = f2bf(vv[j]);
        l[j] = f2bf(vv[j] - bf2f(h[j]));
    }
    reinterpret_cast<ushort4*>(hi)[idx] = *reinterpret_cast<ushort4*>(h);
    reinterpret_cast<ushort4*>(lo)[idx] = *reinterpret_cast<ushort4*>(l);
}

template <bool SPLIT>
__global__ __launch_bounds__(256) void transpose_cast_kernel(
    const float* __restrict__ in, ushort_t* __restrict__ hi, ushort_t* __restrict__ lo,
    int R, int C)
{
    __shared__ float tile[32][33];
    int bc = blockIdx.x * 32;
    int br = blockIdx.y * 32;
    int tx = threadIdx.x, ty = threadIdx.y;   // (32, 8)
#pragma unroll
    for (int r = ty; r < 32; r += 8)
        tile[r][tx] = in[(size_t)(br + r) * C + bc + tx];
    __syncthreads();
#pragma unroll
    for (int c = ty; c < 32; c += 8) {
        float v = tile[tx][c];
        size_t o = (size_t)(bc + c) * R + br + tx;
        ushort_t h = f2bf(v);
        hi[o] = h;
        if (SPLIT) lo[o] = f2bf(v - bf2f(h));
    }
}

// ---------------- split GEMM: C = Ah@Bh^T + Ah@Bl^T + Al@Bh^T ----------------
// Round-1 verified 128x128 / BK=64 / 4-wave structure, but stages the 4
// distinct tiles (Ah,Al,Bh,Bl) ONCE per K-step and runs 3 MFMA passes with
// register reuse — 3x FLOP per barrier, -33% staged bytes vs 3 serial pairs.
// OM: 0 = f32 out, 2 = split bf16 (hi+lo) out. CAUSAL: skip blocks above diag.

template <int OM, bool CAUSAL>
__global__ __launch_bounds__(256, 2) void gemm_split_kernel(
    const ushort_t* __restrict__ Ah, const ushort_t* __restrict__ Al,
    const ushort_t* __restrict__ Bh, const ushort_t* __restrict__ Bl,
    int K, int ldc,
    float* __restrict__ Cf, ushort_t* __restrict__ Ch, ushort_t* __restrict__ Cl)
{
    const int bx = blockIdx.x;   // N tile
    const int by = blockIdx.y;   // M tile
    if (CAUSAL && bx * 128 > by * 128 + 127) return;

    __shared__ ushort_t AHs[128 * 64];   // 16 KB each, chunk-XOR swizzled
    __shared__ ushort_t ALs[128 * 64];
    __shared__ ushort_t BHs[128 * 64];
    __shared__ ushort_t BLs[128 * 64];

    const int t = threadIdx.x;
    const int l = t & 63;
    const int w = t >> 6;
    const int wr = w >> 1;   // wave row (0..1) -> 64 rows of M
    const int wc = w & 1;    // wave col (0..1) -> 64 cols of N

    f32x4 acc[4][4];
#pragma unroll
    for (int m = 0; m < 4; ++m)
#pragma unroll
        for (int n = 0; n < 4; ++n) acc[m][n] = (f32x4){0.f, 0.f, 0.f, 0.f};

    const size_t arow0 = (size_t)by * 128;
    const size_t brow0 = (size_t)bx * 128;

    auto stage1 = [&](const ushort_t* src, ushort_t* dst, size_t row0, int kt) {
        // 128 rows x 8 chunks(16B); linear LDS dest, inverse-swizzled source.
#pragma unroll
        for (int i = 0; i < 4; ++i) {
            int f = i * 256 + t;
            int r = f >> 3;
            int cch = (f & 7) ^ (r & 7);
            gload16(src + (row0 + r) * (size_t)K + kt + cch * 8,
                    (char*)dst + (i * 256 + w * 64) * 16);
        }
    };
    auto rdf = [&](short8* d, const ushort_t* base, int rbase, int kk) {
#pragma unroll
        for (int m = 0; m < 4; ++m) {
            int row = rbase + m * 16 + (l & 15);
            int gby = kk * 64 + (l >> 4) * 16;
            d[m] = *(const short8*)((const char*)base + row * 128 +
                                    (gby ^ ((row & 7) * 16)));
        }
    };
    auto mm16 = [&](const short8* a, const short8* b) {
#pragma unroll
        for (int m = 0; m < 4; ++m)
#pragma unroll
            for (int n = 0; n < 4; ++n)
                acc[m][n] = __builtin_amdgcn_mfma_f32_16x16x32_bf16(
                    a[m], b[n], acc[m][n], 0, 0, 0);
    };

    for (int kt = 0; kt < K; kt += 64) {
        __syncthreads();
        stage1(Ah, AHs, arow0, kt);
        stage1(Al, ALs, arow0, kt);
        stage1(Bh, BHs, brow0, kt);
        stage1(Bl, BLs, brow0, kt);
        __syncthreads();

#pragma unroll
        for (int kk = 0; kk < 2; ++kk) {
            short8 ah[4], bh[4], x[4];
            rdf(ah, AHs, wr * 64, kk);
            rdf(bh, BHs, wc * 64, kk);
            mm16(ah, bh);            // hi * hi
            rdf(x, BLs, wc * 64, kk);
            mm16(ah, x);             // hi * lo
            rdf(x, ALs, wr * 64, kk);
            mm16(x, bh);             // lo * hi
        }
    }

    // epilogue: C/D layout col = lane&15, row = (lane>>4)*4 + reg
    const int r0 = by * 128 + wr * 64 + ((l >> 4) << 2);
    const int c0 = bx * 128 + wc * 64 + (l & 15);
#pragma unroll
    for (int m = 0; m < 4; ++m)
#pragma unroll
        for (int n = 0; n < 4; ++n)
#pragma unroll
            for (int j = 0; j < 4; ++j) {
                size_t o = (size_t)(r0 + m * 16 + j) * ldc + (c0 + n * 16);
                float v = acc[m][n][j];
                if (OM == 0) {
                    Cf[o] = v;
                } else {
                    ushort_t hh = f2bf(v);
                    Ch[o] = hh;
                    Cl[o] = f2bf(v - bf2f(hh));
                }
            }
}

// ---------------- plain GEMM: C[M][N] = A @ B^T (round-1 verified) ----------------
// OM: 0 = f32 out, 1 = bf16 out. CKLIM: limit K to (by+1)*128 (causal attn rows).

template <int OM, bool CKLIM>
__global__ __launch_bounds__(256, 2) void gemm_bt_kernel(
    const ushort_t* __restrict__ A, const ushort_t* __restrict__ B,
    int K, int ldc,
    float* __restrict__ Cf, ushort_t* __restrict__ Ch)
{
    const int bx = blockIdx.x;
    const int by = blockIdx.y;

    __shared__ ushort_t Asm[128 * 64];
    __shared__ ushort_t Bsm[128 * 64];

    const int t = threadIdx.x;
    const int l = t & 63;
    const int w = t >> 6;
    const int wr = w >> 1;
    const int wc = w & 1;

    f32x4 acc[4][4];
#pragma unroll
    for (int m = 0; m < 4; ++m)
#pragma unroll
        for (int n = 0; n < 4; ++n) acc[m][n] = (f32x4){0.f, 0.f, 0.f, 0.f};

    const size_t arow0 = (size_t)by * 128;
    const size_t brow0 = (size_t)bx * 128;

    int kend = K;
    if (CKLIM) { int lim = (by + 1) * 128; if (lim < kend) kend = lim; }

    for (int kt = 0; kt < kend; kt += 64) {
        __syncthreads();
#pragma unroll
        for (int i = 0; i < 4; ++i) {
            int f = i * 256 + t;
            int r = f >> 3;
            int cch = (f & 7) ^ (r & 7);
            gload16(A + (arow0 + r) * (size_t)K + kt + cch * 8,
                    (char*)Asm + (i * 256 + w * 64) * 16);
            gload16(B + (brow0 + r) * (size_t)K + kt + cch * 8,
                    (char*)Bsm + (i * 256 + w * 64) * 16);
        }
        __syncthreads();

#pragma unroll
        for (int kk = 0; kk < 2; ++kk) {
            short8 af[4], bfr[4];
#pragma unroll
            for (int m = 0; m < 4; ++m) {
                int row = wr * 64 + m * 16 + (l & 15);
                int gby = kk * 64 + (l >> 4) * 16;
                af[m] = *(const short8*)((const char*)Asm + row * 128 +
                                         (gby ^ ((row & 7) * 16)));
            }
#pragma unroll
            for (int n = 0; n < 4; ++n) {
                int row = wc * 64 + n * 16 + (l & 15);
                int gby = kk * 64 + (l >> 4) * 16;
                bfr[n] = *(const short8*)((const char*)Bsm + row * 128 +
                                          (gby ^ ((row & 7) * 16)));
            }
#pragma unroll
            for (int m = 0; m < 4; ++m)
#pragma unroll
                for (int n = 0; n < 4; ++n)
                    acc[m][n] = __builtin_amdgcn_mfma_f32_16x16x32_bf16(
                        af[m], bfr[n], acc[m][n], 0, 0, 0);
        }
    }

    const int r0 = by * 128 + wr * 64 + ((l >> 4) << 2);
    const int c0 = bx * 128 + wc * 64 + (l & 15);
#pragma unroll
    for (int m = 0; m < 4; ++m)
#pragma unroll
        for (int n = 0; n < 4; ++n)
#pragma unroll
            for (int j = 0; j < 4; ++j) {
                size_t o = (size_t)(r0 + m * 16 + j) * ldc + (c0 + n * 16);
                if (OM == 0) Cf[o] = acc[m][n][j];
                else         Ch[o] = f2bf(acc[m][n][j]);
            }
}

// ---------------- causal row softmax ----------------

__device__ __forceinline__ float waveMax(float v) {
#pragma unroll
    for (int o = 32; o > 0; o >>= 1) v = fmaxf(v, __shfl_xor(v, o, 64));
    return v;
}
__device__ __forceinline__ float waveSum(float v) {
#pragma unroll
    for (int o = 32; o > 0; o >>= 1) v += __shfl_xor(v, o, 64);
    return v;
}

__global__ __launch_bounds__(256) void softmax_kernel(
    const float* __restrict__ S, ushort_t* __restrict__ A)
{
    const int i = blockIdx.x;
    __shared__ float row[N_CTX];
    __shared__ float red[8];
    const int t = threadIdx.x;
    const int len = i + 1;
    const float* Srow = S + (size_t)i * N_CTX;

    float m = -3.4e38f;
    for (int j = t; j < len; j += 256) {
        float v = Srow[j];
        row[j] = v;
        m = fmaxf(m, v);
    }
    m = waveMax(m);
    if ((t & 63) == 0) red[t >> 6] = m;
    __syncthreads();
    m = fmaxf(fmaxf(red[0], red[1]), fmaxf(red[2], red[3]));

    float s = 0.f;
    for (int j = t; j < len; j += 256) {
        float e = __expf(row[j] - m);
        row[j] = e;
        s += e;
    }
    s = waveSum(s);
    __syncthreads();
    if ((t & 63) == 0) red[t >> 6] = s;
    __syncthreads();
    float inv = 1.f / (red[0] + red[1] + red[2] + red[3]);

    ushort_t* Arow = A + (size_t)i * N_CTX;
    for (int j = t; j < N_CTX; j += 256)
        Arow[j] = (j < len) ? f2bf(row[j] * inv) : (ushort_t)0;
}

// ---------------- launcher ----------------

extern "C" void kernel_launch(void* const* d_in, const int* in_sizes, int n_in,
                              void* d_out, int out_size, void* d_ws, size_t ws_size,
                              hipStream_t stream)
{
    const float* E  = (const float*)d_in[0];
    const float* qk = (const float*)d_in[1];
    const float* ov = (const float*)d_in[2];
    float* out = (float*)d_out;

    char* ws = (char*)d_ws;
    size_t off = 0;
    auto take = [&](size_t bytes) -> char* {
        char* p = ws + off;
        off += (bytes + 255) & ~(size_t)255;
        return p;
    };

    ushort_t* Ehi   = (ushort_t*)take((size_t)N_CTX * DM * 2);
    ushort_t* Elo   = (ushort_t*)take((size_t)N_CTX * DM * 2);
    ushort_t* Et    = (ushort_t*)take((size_t)N_CTX * DM * 2);
    ushort_t* QKthi = (ushort_t*)take((size_t)DM * DM * 2);
    ushort_t* QKtlo = (ushort_t*)take((size_t)DM * DM * 2);
    ushort_t* OVt   = (ushort_t*)take((size_t)DM * DM * 2);
    ushort_t* Qhi   = (ushort_t*)take((size_t)N_CTX * DM * 2);
    ushort_t* Qlo   = (ushort_t*)take((size_t)N_CTX * DM * 2);
    float*    S     = (float*)take((size_t)N_CTX * N_CTX * 4);
    ushort_t* Attn  = (ushort_t*)take((size_t)N_CTX * N_CTX * 2);
    ushort_t* Hbf   = (ushort_t*)take((size_t)N_CTX * DM * 2);
    (void)ws_size; (void)in_sizes; (void)n_in; (void)out_size;

    // 1. casts
    split_cast_kernel<<<dim3((N_CTX * DM / 4) / 256), 256, 0, stream>>>(E, Ehi, Elo, N_CTX * DM / 4);
    transpose_cast_kernel<true ><<<dim3(DM / 32, DM / 32),    dim3(32, 8), 0, stream>>>(qk, QKthi, QKtlo, DM, DM);
    transpose_cast_kernel<false><<<dim3(DM / 32, DM / 32),    dim3(32, 8), 0, stream>>>(ov, OVt, nullptr, DM, DM);
    transpose_cast_kernel<false><<<dim3(DM / 32, N_CTX / 32), dim3(32, 8), 0, stream>>>(E, Et, nullptr, N_CTX, DM);

    // 2. Q = E @ qk  (fused 3-pass split, split bf16 out)
    gemm_split_kernel<2, false><<<dim3(DM / 128, N_CTX / 128), 256, 0, stream>>>(
        Ehi, Elo, QKthi, QKtlo, DM, DM, nullptr, Qhi, Qlo);

    // 3. S = Q @ E^T  (fused 3-pass split, causal block skip, f32 out)
    gemm_split_kernel<0, true><<<dim3(N_CTX / 128, N_CTX / 128), 256, 0, stream>>>(
        Qhi, Qlo, Ehi, Elo, DM, N_CTX, S, nullptr, nullptr);

    // 4. attn = causal softmax(S), bf16
    softmax_kernel<<<N_CTX, 256, 0, stream>>>(S, Attn);

    // 5. H = attn @ E  (bf16 out, causal K-limit)
    gemm_bt_kernel<1, true><<<dim3(DM / 128, N_CTX / 128), 256, 0, stream>>>(
        Attn, Et, N_CTX, DM, nullptr, Hbf);

    // 6. out = H @ ov  (f32 out)
    gemm_bt_kernel<0, false><<<dim3(DM / 128, N_CTX / 128), 256, 0, stream>>>(
        Hbf, OVt, DM, DM, out, nullptr);
}

// Round 7
// 460.066 us; speedup vs baseline: 2.9967x; 1.0195x over previous
//
#include <hip/hip_runtime.h>
#include <hip/hip_bf16.h>
#include <math.h>

#define N_CTX 4096
#define DM    2048

typedef __attribute__((ext_vector_type(8))) short short8;
typedef __attribute__((ext_vector_type(4))) float f32x4;
typedef unsigned short ushort_t;

__device__ __forceinline__ ushort_t f2bf(float x) {
    __hip_bfloat16 h = __float2bfloat16(x);
    return __builtin_bit_cast(ushort_t, h);
}
__device__ __forceinline__ float bf2f(ushort_t u) {
    return __bfloat162float(__builtin_bit_cast(__hip_bfloat16, u));
}

__device__ __forceinline__ void gload16(const void* g, void* l) {
    __builtin_amdgcn_global_load_lds((const __attribute__((address_space(1))) void*)g,
                                     (__attribute__((address_space(3))) void*)l,
                                     16, 0, 0);
}

// ---------------- cast kernels ----------------

__global__ __launch_bounds__(256) void split_cast_kernel(
    const float* __restrict__ in, ushort_t* __restrict__ hi, ushort_t* __restrict__ lo, int n4)
{
    int idx = blockIdx.x * 256 + threadIdx.x;
    if (idx >= n4) return;
    float4 v = reinterpret_cast<const float4*>(in)[idx];
    float vv[4] = {v.x, v.y, v.z, v.w};
    ushort_t h[4], l[4];
#pragma unroll
    for (int j = 0; j < 4; ++j) {
        h[j] = f2bf(vv[j]);
        l[j] = f2bf(vv[j] - bf2f(h[j]));
    }
    reinterpret_cast<ushort4*>(hi)[idx] = *reinterpret_cast<ushort4*>(h);
    reinterpret_cast<ushort4*>(lo)[idx] = *reinterpret_cast<ushort4*>(l);
}

template <bool SPLIT>
__global__ __launch_bounds__(256) void transpose_cast_kernel(
    const float* __restrict__ in, ushort_t* __restrict__ hi, ushort_t* __restrict__ lo,
    int R, int C)
{
    __shared__ float tile[32][33];
    int bc = blockIdx.x * 32;
    int br = blockIdx.y * 32;
    int tx = threadIdx.x, ty = threadIdx.y;   // (32, 8)
#pragma unroll
    for (int r = ty; r < 32; r += 8)
        tile[r][tx] = in[(size_t)(br + r) * C + bc + tx];
    __syncthreads();
#pragma unroll
    for (int c = ty; c < 32; c += 8) {
        float v = tile[tx][c];
        size_t o = (size_t)(bc + c) * R + br + tx;
        ushort_t h = f2bf(v);
        hi[o] = h;
        if (SPLIT) lo[o] = f2bf(v - bf2f(h));
    }
}

// ---------------- split GEMM (dbuf): C = Ah@Bh^T + Ah@Bl^T + Al@Bh^T ----------------
// 128x128 tile, BK=32, 4 waves (2x2), double-buffered LDS (4 tiles x 8KB x 2 = 64KB).
// Minimum-2-phase pipeline (T3): STAGE(t+1) issued BEFORE compute(t); ONE
// __syncthreads per K-step (drains vmcnt for staged tile + write-after-read).
// BK=32 swizzle: 64B rows (4 chunks of 16B); LDS slot c holds global chunk
// c ^ ((row>>1)&3)  -> exact 2-way bank aliasing on ds_read_b128 (free).
// OM: 0 = f32 out, 2 = split bf16 out. TRI: triangular 1D grid (causal S).

template <int OM, bool TRI>
__global__ __launch_bounds__(256, 2) void gemm_split_kernel(
    const ushort_t* __restrict__ Ah, const ushort_t* __restrict__ Al,
    const ushort_t* __restrict__ Bh, const ushort_t* __restrict__ Bl,
    int K, int ldc,
    float* __restrict__ Cf, ushort_t* __restrict__ Ch, ushort_t* __restrict__ Cl)
{
    int bx, by;
    if (TRI) {
        int i = blockIdx.x;
        int b = (int)((sqrtf(8.f * (float)i + 1.f) - 1.f) * 0.5f);
        while ((b + 1) * (b + 2) / 2 <= i) ++b;
        while (b * (b + 1) / 2 > i) --b;
        by = b; bx = i - b * (b + 1) / 2;
    } else {
        bx = blockIdx.x; by = blockIdx.y;
    }

    __shared__ ushort_t lds[2][4][128 * 32];   // [buf][AH,AL,BH,BL]

    const int t = threadIdx.x;
    const int l = t & 63;
    const int w = t >> 6;
    const int wr = w >> 1;   // 0..1 -> 64-row band
    const int wc = w & 1;    // 0..1 -> 64-col band
    const int lr = l & 15;
    const int lc = l >> 4;

    f32x4 acc[4][4];
#pragma unroll
    for (int m = 0; m < 4; ++m)
#pragma unroll
        for (int n = 0; n < 4; ++n) acc[m][n] = (f32x4){0.f, 0.f, 0.f, 0.f};

    const size_t arow0 = (size_t)by * 128;
    const size_t brow0 = (size_t)bx * 128;

    auto stg1 = [&](const ushort_t* src, ushort_t* dst, size_t row0, int kt) {
        // 128 rows x 4 chunks(16B) = 512 chunks; 2 gloads/thread.
#pragma unroll
        for (int i2 = 0; i2 < 2; ++i2) {
            int f = i2 * 256 + t;
            int r = f >> 2, c = f & 3;
            gload16(src + (row0 + r) * (size_t)K + kt + ((c ^ ((r >> 1) & 3)) << 3),
                    (char*)dst + f * 16);
        }
    };
    auto stage = [&](int kt, int buf) {
        stg1(Ah, lds[buf][0], arow0, kt);
        stg1(Al, lds[buf][1], arow0, kt);
        stg1(Bh, lds[buf][2], brow0, kt);
        stg1(Bl, lds[buf][3], brow0, kt);
    };
    auto rdf = [&](short8* d, const ushort_t* base, int rbase) {
#pragma unroll
        for (int m = 0; m < 4; ++m) {
            int row = rbase + m * 16 + lr;
            d[m] = *(const short8*)((const char*)base + row * 64 +
                                    ((lc ^ ((row >> 1) & 3)) << 4));
        }
    };
    auto mm16 = [&](const short8* a, const short8* b) {
#pragma unroll
        for (int m = 0; m < 4; ++m)
#pragma unroll
            for (int n = 0; n < 4; ++n)
                acc[m][n] = __builtin_amdgcn_mfma_f32_16x16x32_bf16(
                    a[m], b[n], acc[m][n], 0, 0, 0);
    };

    stage(0, 0);
    __syncthreads();
    const int nt = K >> 5;
    for (int tt = 0; tt < nt; ++tt) {
        const int buf = tt & 1;
        if (tt + 1 < nt) stage((tt + 1) << 5, buf ^ 1);
        short8 ah[4], bh[4], x[4];
        rdf(ah, lds[buf][0], wr * 64);
        rdf(bh, lds[buf][2], wc * 64);
        mm16(ah, bh);            // hi * hi
        rdf(x, lds[buf][3], wc * 64);
        mm16(ah, x);             // hi * lo
        rdf(x, lds[buf][1], wr * 64);
        mm16(x, bh);             // lo * hi
        __syncthreads();         // drains staged vmcnt + protects buf overwrite
    }

    // epilogue: C/D layout col = lane&15, row = (lane>>4)*4 + reg
    const int r0 = by * 128 + wr * 64 + (lc << 2);
    const int c0 = bx * 128 + wc * 64 + lr;
#pragma unroll
    for (int m = 0; m < 4; ++m)
#pragma unroll
        for (int n = 0; n < 4; ++n)
#pragma unroll
            for (int j = 0; j < 4; ++j) {
                size_t o = (size_t)(r0 + m * 16 + j) * ldc + (c0 + n * 16);
                float v = acc[m][n][j];
                if (OM == 0) {
                    Cf[o] = v;
                } else {
                    ushort_t hh = f2bf(v);
                    Ch[o] = hh;
                    Cl[o] = f2bf(v - bf2f(hh));
                }
            }
}

// ---------------- plain GEMM (dbuf): C[M][N] = A @ B^T ----------------
// 128x128 tile, BK=64, dbuf (2 tiles x 16KB x 2 = 64KB), 1 barrier per step.
// OM: 0 = f32 out, 1 = bf16 out. CKLIM: limit K to (by+1)*128 (causal attn rows).

template <int OM, bool CKLIM>
__global__ __launch_bounds__(256, 2) void gemm_bt_kernel(
    const ushort_t* __restrict__ A, const ushort_t* __restrict__ B,
    int K, int ldc,
    float* __restrict__ Cf, ushort_t* __restrict__ Ch)
{
    const int bx = blockIdx.x;
    const int by = blockIdx.y;

    __shared__ ushort_t lds[2][2][128 * 64];   // [buf][A,B] 64KB

    const int t = threadIdx.x;
    const int l = t & 63;
    const int w = t >> 6;
    const int wr = w >> 1;
    const int wc = w & 1;

    f32x4 acc[4][4];
#pragma unroll
    for (int m = 0; m < 4; ++m)
#pragma unroll
        for (int n = 0; n < 4; ++n) acc[m][n] = (f32x4){0.f, 0.f, 0.f, 0.f};

    const size_t arow0 = (size_t)by * 128;
    const size_t brow0 = (size_t)bx * 128;

    int kend = K;
    if (CKLIM) { int lim = (by + 1) * 128; if (lim < kend) kend = lim; }

    auto stage = [&](int kt, int buf) {
        // per tile: 128 rows x 8 chunks = 1024 chunks; 4 gloads/thread.
#pragma unroll
        for (int i2 = 0; i2 < 4; ++i2) {
            int f = i2 * 256 + t;
            int r = f >> 3, c = f & 7;
            gload16(A + (arow0 + r) * (size_t)K + kt + ((c ^ (r & 7)) << 3),
                    (char*)lds[buf][0] + f * 16);
            gload16(B + (brow0 + r) * (size_t)K + kt + ((c ^ (r & 7)) << 3),
                    (char*)lds[buf][1] + f * 16);
        }
    };

    stage(0, 0);
    __syncthreads();
    const int nt = kend >> 6;
    for (int tt = 0; tt < nt; ++tt) {
        const int buf = tt & 1;
        if (tt + 1 < nt) stage((tt + 1) << 6, buf ^ 1);
#pragma unroll
        for (int kk = 0; kk < 2; ++kk) {
            short8 af[4], bfr[4];
#pragma unroll
            for (int m = 0; m < 4; ++m) {
                int row = wr * 64 + m * 16 + (l & 15);
                int gby = kk * 64 + (l >> 4) * 16;
                af[m] = *(const short8*)((const char*)lds[buf][0] + row * 128 +
                                         (gby ^ ((row & 7) * 16)));
            }
#pragma unroll
            for (int n = 0; n < 4; ++n) {
                int row = wc * 64 + n * 16 + (l & 15);
                int gby = kk * 64 + (l >> 4) * 16;
                bfr[n] = *(const short8*)((const char*)lds[buf][1] + row * 128 +
                                          (gby ^ ((row & 7) * 16)));
            }
#pragma unroll
            for (int m = 0; m < 4; ++m)
#pragma unroll
                for (int n = 0; n < 4; ++n)
                    acc[m][n] = __builtin_amdgcn_mfma_f32_16x16x32_bf16(
                        af[m], bfr[n], acc[m][n], 0, 0, 0);
        }
        __syncthreads();
    }

    const int r0 = by * 128 + wr * 64 + ((l >> 4) << 2);
    const int c0 = bx * 128 + wc * 64 + (l & 15);
#pragma unroll
    for (int m = 0; m < 4; ++m)
#pragma unroll
        for (int n = 0; n < 4; ++n)
#pragma unroll
            for (int j = 0; j < 4; ++j) {
                size_t o = (size_t)(r0 + m * 16 + j) * ldc + (c0 + n * 16);
                if (OM == 0) Cf[o] = acc[m][n][j];
                else         Ch[o] = f2bf(acc[m][n][j]);
            }
}

// ---------------- causal row softmax ----------------

__device__ __forceinline__ float waveMax(float v) {
#pragma unroll
    for (int o = 32; o > 0; o >>= 1) v = fmaxf(v, __shfl_xor(v, o, 64));
    return v;
}
__device__ __forceinline__ float waveSum(float v) {
#pragma unroll
    for (int o = 32; o > 0; o >>= 1) v += __shfl_xor(v, o, 64);
    return v;
}

__global__ __launch_bounds__(256) void softmax_kernel(
    const float* __restrict__ S, ushort_t* __restrict__ A)
{
    const int i = blockIdx.x;
    __shared__ float row[N_CTX];
    __shared__ float red[8];
    const int t = threadIdx.x;
    const int len = i + 1;
    const float* Srow = S + (size_t)i * N_CTX;

    float m = -3.4e38f;
    for (int j = t; j < len; j += 256) {
        float v = Srow[j];
        row[j] = v;
        m = fmaxf(m, v);
    }
    m = waveMax(m);
    if ((t & 63) == 0) red[t >> 6] = m;
    __syncthreads();
    m = fmaxf(fmaxf(red[0], red[1]), fmaxf(red[2], red[3]));

    float s = 0.f;
    for (int j = t; j < len; j += 256) {
        float e = __expf(row[j] - m);
        row[j] = e;
        s += e;
    }
    s = waveSum(s);
    __syncthreads();
    if ((t & 63) == 0) red[t >> 6] = s;
    __syncthreads();
    float inv = 1.f / (red[0] + red[1] + red[2] + red[3]);

    ushort_t* Arow = A + (size_t)i * N_CTX;
    for (int j = t; j < N_CTX; j += 256)
        Arow[j] = (j < len) ? f2bf(row[j] * inv) : (ushort_t)0;
}

// ---------------- launcher ----------------

extern "C" void kernel_launch(void* const* d_in, const int* in_sizes, int n_in,
                              void* d_out, int out_size, void* d_ws, size_t ws_size,
                              hipStream_t stream)
{
    const float* E  = (const float*)d_in[0];
    const float* qk = (const float*)d_in[1];
    const float* ov = (const float*)d_in[2];
    float* out = (float*)d_out;

    char* ws = (char*)d_ws;
    size_t off = 0;
    auto take = [&](size_t bytes) -> char* {
        char* p = ws + off;
        off += (bytes + 255) & ~(size_t)255;
        return p;
    };

    ushort_t* Ehi   = (ushort_t*)take((size_t)N_CTX * DM * 2);
    ushort_t* Elo   = (ushort_t*)take((size_t)N_CTX * DM * 2);
    ushort_t* Et    = (ushort_t*)take((size_t)N_CTX * DM * 2);
    ushort_t* QKthi = (ushort_t*)take((size_t)DM * DM * 2);
    ushort_t* QKtlo = (ushort_t*)take((size_t)DM * DM * 2);
    ushort_t* OVt   = (ushort_t*)take((size_t)DM * DM * 2);
    ushort_t* Qhi   = (ushort_t*)take((size_t)N_CTX * DM * 2);
    ushort_t* Qlo   = (ushort_t*)take((size_t)N_CTX * DM * 2);
    float*    S     = (float*)take((size_t)N_CTX * N_CTX * 4);
    ushort_t* Attn  = (ushort_t*)take((size_t)N_CTX * N_CTX * 2);
    ushort_t* Hbf   = (ushort_t*)take((size_t)N_CTX * DM * 2);
    (void)ws_size; (void)in_sizes; (void)n_in; (void)out_size;

    // 1. casts
    split_cast_kernel<<<dim3((N_CTX * DM / 4) / 256), 256, 0, stream>>>(E, Ehi, Elo, N_CTX * DM / 4);
    transpose_cast_kernel<true ><<<dim3(DM / 32, DM / 32),    dim3(32, 8), 0, stream>>>(qk, QKthi, QKtlo, DM, DM);
    transpose_cast_kernel<false><<<dim3(DM / 32, DM / 32),    dim3(32, 8), 0, stream>>>(ov, OVt, nullptr, DM, DM);
    transpose_cast_kernel<false><<<dim3(DM / 32, N_CTX / 32), dim3(32, 8), 0, stream>>>(E, Et, nullptr, N_CTX, DM);

    // 2. Q = E @ qk  (fused 3-pass split, dbuf, split bf16 out)
    gemm_split_kernel<2, false><<<dim3(DM / 128, N_CTX / 128), 256, 0, stream>>>(
        Ehi, Elo, QKthi, QKtlo, DM, DM, nullptr, Qhi, Qlo);

    // 3. S = Q @ E^T  (fused 3-pass split, dbuf, triangular grid, f32 out)
    gemm_split_kernel<0, true><<<dim3(32 * 33 / 2), 256, 0, stream>>>(
        Qhi, Qlo, Ehi, Elo, DM, N_CTX, S, nullptr, nullptr);

    // 4. attn = causal softmax(S), bf16
    softmax_kernel<<<N_CTX, 256, 0, stream>>>(S, Attn);

    // 5. H = attn @ E  (bf16 out, causal K-limit, dbuf)
    gemm_bt_kernel<1, true><<<dim3(DM / 128, N_CTX / 128), 256, 0, stream>>>(
        Attn, Et, N_CTX, DM, nullptr, Hbf);

    // 6. out = H @ ov  (f32 out, dbuf)
    gemm_bt_kernel<0, false><<<dim3(DM / 128, N_CTX / 128), 256, 0, stream>>>(
        Hbf, OVt, DM, DM, out, nullptr);
}